// Round 5
// baseline (274.668 us; speedup 1.0000x reference)
//
#include <hip/hip_runtime.h>

#define NB 62
#define NC 5
#define KTOP 49

typedef unsigned short ushort_t;
typedef unsigned int uint_t;

__device__ __forceinline__ float sigmf(float x) {
    return 1.0f / (1.0f + __expf(-x));
}

__device__ __forceinline__ ushort_t f2b(float f) {   // f32 -> bf16 (RNE)
    union { float f; uint_t u; } cv; cv.f = f;
    uint_t r = (cv.u + 0x7fffu + ((cv.u >> 16) & 1u)) >> 16;
    return (ushort_t)r;
}
__device__ __forceinline__ float b2f(ushort_t h) {   // bf16 -> f32 (exact)
    union { uint_t u; float f; } cv; cv.u = ((uint_t)h) << 16;
    return cv.f;
}
__device__ __forceinline__ float blo(uint_t w) {
    union { uint_t u; float f; } cv; cv.u = w << 16; return cv.f;
}
__device__ __forceinline__ float bhi(uint_t w) {
    union { uint_t u; float f; } cv; cv.u = w & 0xffff0000u; return cv.f;
}

__device__ __forceinline__ float tmax62(const float* a) {
    float t0 = a[0], t1 = a[1], t2 = a[2], t3 = a[3];
    #pragma unroll
    for (int m = 4; m < 60; m += 4) {
        t0 = fmaxf(t0, a[m]);     t1 = fmaxf(t1, a[m + 1]);
        t2 = fmaxf(t2, a[m + 2]); t3 = fmaxf(t3, a[m + 3]);
    }
    t0 = fmaxf(t0, a[60]); t1 = fmaxf(t1, a[61]);
    return fmaxf(fmaxf(t0, t1), fmaxf(t2, t3));
}
__device__ __forceinline__ float tsum62(const float* a) {
    float t0 = a[0], t1 = a[1], t2 = a[2], t3 = a[3];
    #pragma unroll
    for (int m = 4; m < 60; m += 4) {
        t0 += a[m]; t1 += a[m + 1]; t2 += a[m + 2]; t3 += a[m + 3];
    }
    t0 += a[60]; t1 += a[61];
    return (t0 + t1) + (t2 + t3);
}

// Repack FC weights into d_ws: fc1w[64][930] -> bf16 [117][64][8] (zero-pad to 936),
// fc2w[64][64] -> f32 [16][64][4]. Makes the FC loops fully coalesced.
__global__ void repack_kernel(const float* __restrict__ fc1w,
                              const float* __restrict__ fc2w,
                              ushort_t* __restrict__ w1o,
                              float* __restrict__ w2o) {
    const int i = blockIdx.x * 256 + threadIdx.x;
    if (i < 117 * 64 * 8) {
        const int j = i & 7, o = (i >> 3) & 63, i8 = i >> 9;
        const int src = i8 * 8 + j;
        const float v = (src < 930) ? fc1w[o * 930 + src] : 0.0f;
        w1o[i] = f2b(v);
    } else if (i < 117 * 64 * 8 + 16 * 64 * 4) {
        const int i2 = i - 117 * 64 * 8;
        const int j = i2 & 3, o = (i2 >> 2) & 63, k4 = i2 >> 8;
        w2o[i2] = fc2w[o * 64 + k4 * 4 + j];
    }
}

// One DGCN layer. fin/fout are per-thread register arrays (node = lane id);
// force-inlined so all indexing stays compile-time (no scratch).
__device__ __forceinline__ void dgcn_layer(
    const int tid,
    const float* __restrict__ fin, float* __restrict__ fout,
    const float* __restrict__ conv_w, const float* __restrict__ conv_b,
    const float* __restrict__ memp,
    const float* __restrict__ gfc_w, const float* __restrict__ gfc_b,
    const float* __restrict__ gcn_w, const float* __restrict__ gcn_b,
    ushort_t* __restrict__ s_adjh, float (*__restrict__ s_xm)[12])
{
    const float scale = 0.44721359549995793f; // 1/sqrt(5)

    // stage mem transposed: s_xm[m][4+c] (c<4), s_xm[m][9] (c==4)
    for (int i = tid; i < NC * NB; i += 64) {
        const int c = i / NB, m = i - c * NB;
        s_xm[m][c < 4 ? 4 + c : 9] = memp[i];
    }

    float cw[25], cb[5];
    #pragma unroll
    for (int i = 0; i < 25; ++i) cw[i] = conv_w[i];
    #pragma unroll
    for (int i = 0; i < 5; ++i)  cb[i] = conv_b[i];
    const float w0 = gfc_w[0], w1 = gfc_w[1], b0 = gfc_b[0];

    // ---- conv1x1 on own node ----
    float xo0 = 0, xo1 = 0, xo2 = 0, xo3 = 0, xo4 = 0;
    if (tid < NB) {
        xo0 = cb[0]; xo1 = cb[1]; xo2 = cb[2]; xo3 = cb[3]; xo4 = cb[4];
        #pragma unroll
        for (int c = 0; c < 5; ++c) {
            const float xn = fin[c];
            xo0 = fmaf(cw[c],      xn, xo0);
            xo1 = fmaf(cw[5 + c],  xn, xo1);
            xo2 = fmaf(cw[10 + c], xn, xo2);
            xo3 = fmaf(cw[15 + c], xn, xo3);
            xo4 = fmaf(cw[20 + c], xn, xo4);
        }
        s_xm[tid][0] = xo0; s_xm[tid][1] = xo1; s_xm[tid][2] = xo2;
        s_xm[tid][3] = xo3; s_xm[tid][8] = xo4;
    }
    __syncthreads();

    // ---- row phase: thread n owns row n ----
    if (tid < NB) {
        float r1[NB];
        float r2[64];
        #pragma unroll
        for (int m = 0; m < NB; ++m) {
            const float4 xc03 = *(const float4*)&s_xm[m][0];
            const float4 me03 = *(const float4*)&s_xm[m][4];
            const float2 t45  = *(const float2*)&s_xm[m][8];
            float s1 = xo0 * me03.x + xo1 * me03.y + xo2 * me03.z + xo3 * me03.w + xo4 * t45.y;
            float s2 = xo0 * xc03.x + xo1 * xc03.y + xo2 * xc03.z + xo3 * xc03.w + xo4 * t45.x;
            r1[m] = fmaxf(s1 * scale, 0.0f);
            r2[m] = fmaxf(s2 * scale, 0.0f);
        }
        const float mx1 = tmax62(r1);
        #pragma unroll
        for (int m = 0; m < NB; ++m) r1[m] = __expf(r1[m] - mx1);
        const float inv1 = 1.0f / tsum62(r1);
        const float mx2 = tmax62(r2);
        #pragma unroll
        for (int m = 0; m < NB; ++m) r2[m] = __expf(r2[m] - mx2);
        const float inv2 = 1.0f / tsum62(r2);
        #pragma unroll
        for (int m = 0; m < NB; ++m)
            r1[m] = b0 + (r1[m] * inv1) * w0 + (r2[m] * inv2) * w1;
        const float mxa = tmax62(r1);
        #pragma unroll
        for (int m = 0; m < NB; ++m) r1[m] = __expf(r1[m] - mxa);
        const float inva = 1.0f / tsum62(r1);
        #pragma unroll
        for (int m = 0; m < NB; ++m) r1[m] *= inva;

        // ---- 49th-largest via value-only bitonic sort of a copy ----
        #pragma unroll
        for (int m = 0; m < NB; ++m) r2[m] = r1[m];
        r2[62] = INFINITY; r2[63] = INFINITY;
        #pragma unroll
        for (int k = 2; k <= 64; k <<= 1) {
            #pragma unroll
            for (int j = k >> 1; j > 0; j >>= 1) {
                #pragma unroll
                for (int i = 0; i < 64; ++i) {
                    const int p = i ^ j;
                    if (p > i) {
                        const bool up = ((i & k) == 0);
                        const float a = r2[i], c = r2[p];
                        r2[i] = up ? fminf(a, c) : fmaxf(a, c);
                        r2[p] = up ? fmaxf(a, c) : fminf(a, c);
                    }
                }
            }
        }
        const float vth = r2[13]; // 14th smallest == 49th largest

        // ---- tie-aware selection == jax.lax.top_k (lower index first) ----
        int gc0 = 0, gc1 = 0, gc2 = 0, gc3 = 0;
        #pragma unroll
        for (int m = 0; m < 60; m += 4) {
            gc0 += (r1[m] > vth);     gc1 += (r1[m + 1] > vth);
            gc2 += (r1[m + 2] > vth); gc3 += (r1[m + 3] > vth);
        }
        gc0 += (r1[60] > vth); gc1 += (r1[61] > vth);
        const int G = (gc0 + gc1) + (gc2 + gc3);
        int eq = 0;
        #pragma unroll
        for (int m = 0; m < NB; ++m) {
            const bool e  = (r1[m] == vth);
            const bool ss = (r1[m] > vth) || (e && (G + eq) < KTOP);
            s_adjh[tid * 66 + m] = f2b(ss ? r1[m] : 0.0f);
            eq += e ? 1 : 0;
        }
    }
    __syncthreads();

    // ---- diffusion + gcn mix + skip: thread m computes output column m ----
    if (tid < NB) {
        const int m = tid;
        float y0 = 0, y1 = 0, y2 = 0, y3 = 0, y4 = 0;
        for (int n = 0; n < NB; ++n) {
            const float a = b2f(s_adjh[n * 66 + m]);
            const float4 xv = *(const float4*)&s_xm[n][0];
            const float  xv4 = s_xm[n][8];
            y0 = fmaf(xv.x, a, y0); y1 = fmaf(xv.y, a, y1); y2 = fmaf(xv.z, a, y2);
            y3 = fmaf(xv.w, a, y3); y4 = fmaf(xv4, a, y4);
        }
        float gw[25], gb[5];
        #pragma unroll
        for (int i = 0; i < 25; ++i) gw[i] = gcn_w[i];
        #pragma unroll
        for (int i = 0; i < 5; ++i)  gb[i] = gcn_b[i];
        #pragma unroll
        for (int o = 0; o < 5; ++o) {
            const float z = gb[o] + gw[o * 5 + 0] * y0 + gw[o * 5 + 1] * y1 +
                            gw[o * 5 + 2] * y2 + gw[o * 5 + 3] * y3 + gw[o * 5 + 4] * y4;
            fout[o] = z + fin[o];
        }
    }
    __syncthreads();
}

// waves_per_eu(2,3): budget 256 VGPRs, heuristic may not chase >3 waves/EU
// (round-3 failure: min-only bound -> 84 VGPRs -> 5 MB scratch/dispatch).
// LDS 11160 B -> 14 blocks/CU; VGPR (~160-170) -> 3 waves/EU -> 12 resident.
__global__ void __launch_bounds__(64) __attribute__((amdgpu_waves_per_eu(2, 3)))
encoder_kernel(
    const float* __restrict__ g_x,
    const float* __restrict__ c0w, const float* __restrict__ c0b,
    const float* __restrict__ m0,  const float* __restrict__ f0w,
    const float* __restrict__ f0b, const float* __restrict__ g0w,
    const float* __restrict__ g0b,
    const float* __restrict__ c1w, const float* __restrict__ c1b,
    const float* __restrict__ m1,  const float* __restrict__ f1w,
    const float* __restrict__ f1b, const float* __restrict__ g1w,
    const float* __restrict__ g1b,
    const float* __restrict__ caw1, const float* __restrict__ caw2,
    const float* __restrict__ saw,  const float* __restrict__ sab,
    const float* __restrict__ fc1w, const float* __restrict__ fc1b,
    const float* __restrict__ fc2w, const float* __restrict__ fc2b,
    const ushort_t* __restrict__ w1b, const float* __restrict__ w2p,
    const int use_ws,
    float* __restrict__ g_out)
{
    const int b   = blockIdx.x;
    const int tid = threadIdx.x;

    // LDS 11160 B total; s_g (936 f32) + s_h1 (64 f32) alias the dead adjacency.
    __shared__ __align__(16) ushort_t s_adjh[NB * 66];   // 8184 B
    __shared__ __align__(16) float s_xm[NB][12];          // 2976 B

    float* const s_g  = (float*)s_adjh;        // [936]
    float* const s_h1 = ((float*)s_adjh) + 936;

    // ---- per-thread features (node = lane). Coalesced input load (lane n
    //      reads x[b, c*62+n], consecutive addresses per instruction). ----
    float f0[5], f1[5] = {0, 0, 0, 0, 0}, f2[5] = {0, 0, 0, 0, 0};
    #pragma unroll
    for (int c = 0; c < 5; ++c)
        f0[c] = (tid < NB) ? g_x[(size_t)b * (NC * NB) + c * NB + tid] : 0.0f;

    dgcn_layer(tid, f0, f1, c0w, c0b, m0, f0w, f0b, g0w, g0b, s_adjh, s_xm);
    dgcn_layer(tid, f1, f2, c1w, c1b, m1, f1w, f1b, g1w, g1b, s_adjh, s_xm);

    // ================= CBAM (LDS-free until the s_g write) =================
    // channel max/mean pools via 64-lane shuffle trees
    float mxp[15], avp[15];
    #pragma unroll
    for (int c = 0; c < 15; ++c) {
        const float v = (c < 5) ? f0[c] : (c < 10) ? f1[c - 5] : f2[c - 10];
        float vm = (tid < NB) ? v : -INFINITY;
        float vs = (tid < NB) ? v : 0.0f;
        #pragma unroll
        for (int off = 32; off > 0; off >>= 1) {
            vm = fmaxf(vm, __shfl_xor(vm, off, 64));
            vs += __shfl_xor(vs, off, 64);
        }
        mxp[c] = vm;
        avp[c] = vs * (1.0f / 62.0f);
    }
    // SE MLP, computed redundantly on all lanes (weights are uniform/SGPR)
    float ca[15];
    {
        float hm[3], ha[3];
        #pragma unroll
        for (int o = 0; o < 3; ++o) {
            float am = 0.0f, aa = 0.0f;
            #pragma unroll
            for (int c = 0; c < 15; ++c) {
                const float w = caw1[o * 15 + c];
                am = fmaf(mxp[c], w, am);
                aa = fmaf(avp[c], w, aa);
            }
            hm[o] = fmaxf(am, 0.0f);
            ha[o] = fmaxf(aa, 0.0f);
        }
        #pragma unroll
        for (int c = 0; c < 15; ++c) {
            float t = 0.0f;
            #pragma unroll
            for (int o = 0; o < 3; ++o) t = fmaf(hm[o] + ha[o], caw2[c * 3 + o], t);
            ca[c] = sigmf(t);
        }
    }
    // spatial descriptors on CA-scaled maps; neighbors via lane shuffles
    float og[15];
    float smx = -INFINITY, ssum = 0.0f;
    #pragma unroll
    for (int c = 0; c < 15; ++c) {
        const float fv = (c < 5) ? f0[c] : (c < 10) ? f1[c - 5] : f2[c - 10];
        const float v = fv * ca[c];
        og[c] = v;
        smx = fmaxf(smx, v);
        ssum += v;
    }
    const float smean = ssum * (1.0f / 15.0f);
    const float sxl = __shfl_up(smx, 1, 64),   sml = __shfl_up(smean, 1, 64);
    const float sxr = __shfl_down(smx, 1, 64), smr = __shfl_down(smean, 1, 64);
    const float mskL = (tid > 0) ? 1.0f : 0.0f;
    const float mskR = (tid < NB - 1) ? 1.0f : 0.0f;
    // 3x1 spatial conv (only kw=1 column of the 3x3 survives W=1 padding)
    float t = sab[0];
    t += mskL * (sxl * saw[1] + sml * saw[10]);
    t += smx * saw[4] + smean * saw[13];
    t += mskR * (sxr * saw[7] + smr * saw[16]);
    const float sa = sigmf(t);

    __syncthreads();  // adjacency fully dead; region A becomes s_g/s_h1
    if (tid < NB) {
        #pragma unroll
        for (int c = 0; c < 15; ++c) {
            const float fv = (c < 5) ? f0[c] : (c < 10) ? f1[c - 5] : f2[c - 10];
            s_g[c * NB + tid] = og[c] * sa + fv;
        }
    }
    if (tid < 6) s_g[930 + tid] = 0.0f;   // zero pad to 936
    __syncthreads();

    // ================= FC head =================
    if (use_ws) {
        float acc = fc1b[tid];
        const uint4* w1v = (const uint4*)w1b;
        #pragma unroll 4
        for (int i8 = 0; i8 < 117; ++i8) {
            const uint4 wv = w1v[i8 * 64 + tid];
            const float4 ga  = *(const float4*)&s_g[i8 * 8];
            const float4 gb2 = *(const float4*)&s_g[i8 * 8 + 4];
            acc = fmaf(blo(wv.x), ga.x,  acc);
            acc = fmaf(bhi(wv.x), ga.y,  acc);
            acc = fmaf(blo(wv.y), ga.z,  acc);
            acc = fmaf(bhi(wv.y), ga.w,  acc);
            acc = fmaf(blo(wv.z), gb2.x, acc);
            acc = fmaf(bhi(wv.z), gb2.y, acc);
            acc = fmaf(blo(wv.w), gb2.z, acc);
            acc = fmaf(bhi(wv.w), gb2.w, acc);
        }
        s_h1[tid] = fmaxf(acc, 0.0f);
        __syncthreads();
        float acc2 = fc2b[tid];
        #pragma unroll
        for (int k4 = 0; k4 < 16; ++k4) {
            const float4 wv = *(const float4*)(w2p + k4 * 256 + tid * 4);
            const float4 hv = *(const float4*)&s_h1[k4 * 4];
            acc2 = fmaf(wv.x, hv.x, acc2);
            acc2 = fmaf(wv.y, hv.y, acc2);
            acc2 = fmaf(wv.z, hv.z, acc2);
            acc2 = fmaf(wv.w, hv.w, acc2);
        }
        g_out[(size_t)b * 64 + tid] = fmaxf(acc2, 0.0f);
    } else {
        float acc = fc1b[tid];
        const float* wr = fc1w + (size_t)tid * 930;
        #pragma unroll 4
        for (int i = 0; i < 928; i += 2) {
            const float2 wv = *(const float2*)(wr + i);
            const float2 gv = *(const float2*)(&s_g[i]);
            acc = fmaf(wv.x, gv.x, fmaf(wv.y, gv.y, acc));
        }
        acc += wr[928] * s_g[928] + wr[929] * s_g[929];
        s_h1[tid] = fmaxf(acc, 0.0f);
        __syncthreads();
        float acc2 = fc2b[tid];
        const float* wr2 = fc2w + tid * 64;
        #pragma unroll
        for (int k = 0; k < 64; k += 4) {
            const float4 wv = *(const float4*)(wr2 + k);
            acc2 = fmaf(wv.x, s_h1[k], acc2);
            acc2 = fmaf(wv.y, s_h1[k + 1], acc2);
            acc2 = fmaf(wv.z, s_h1[k + 2], acc2);
            acc2 = fmaf(wv.w, s_h1[k + 3], acc2);
        }
        g_out[(size_t)b * 64 + tid] = fmaxf(acc2, 0.0f);
    }
}

extern "C" void kernel_launch(void* const* d_in, const int* in_sizes, int n_in,
                              void* d_out, int out_size, void* d_ws, size_t ws_size,
                              hipStream_t stream) {
    const float* X    = (const float*)d_in[0];
    const float* C0W  = (const float*)d_in[1];
    const float* C0B  = (const float*)d_in[2];
    const float* M0   = (const float*)d_in[3];
    const float* F0W  = (const float*)d_in[4];
    const float* F0B  = (const float*)d_in[5];
    const float* G0W  = (const float*)d_in[6];
    const float* G0B  = (const float*)d_in[7];
    const float* C1W  = (const float*)d_in[8];
    const float* C1B  = (const float*)d_in[9];
    const float* M1   = (const float*)d_in[10];
    const float* F1W  = (const float*)d_in[11];
    const float* F1B  = (const float*)d_in[12];
    const float* G1W  = (const float*)d_in[13];
    const float* G1B  = (const float*)d_in[14];
    const float* CAW1 = (const float*)d_in[15];
    const float* CAW2 = (const float*)d_in[16];
    const float* SAW  = (const float*)d_in[17];
    const float* SAB  = (const float*)d_in[18];
    const float* FC1W = (const float*)d_in[19];
    const float* FC1B = (const float*)d_in[20];
    const float* FC2W = (const float*)d_in[21];
    const float* FC2B = (const float*)d_in[22];

    const int B = in_sizes[0] / (NC * NB);

    const size_t W1_BYTES = 117 * 64 * 8 * sizeof(ushort_t); // 119808
    const size_t W2_BYTES = 16 * 64 * 4 * sizeof(float);     // 16384
    const int use_ws = (ws_size >= W1_BYTES + W2_BYTES) ? 1 : 0;
    ushort_t* w1b = (ushort_t*)d_ws;
    float*    w2p = (float*)((char*)d_ws + W1_BYTES);

    if (use_ws) {
        repack_kernel<<<250, 256, 0, stream>>>(FC1W, FC2W, w1b, w2p);
    }

    encoder_kernel<<<B, 64, 0, stream>>>(
        X, C0W, C0B, M0, F0W, F0B, G0W, G0B,
        C1W, C1B, M1, F1W, F1B, G1W, G1B,
        CAW1, CAW2, SAW, SAB, FC1W, FC1B, FC2W, FC2B,
        w1b, w2p, use_ws,
        (float*)d_out);
}

// Round 6
// 215.375 us; speedup vs baseline: 1.2753x; 1.2753x over previous
//
#include <hip/hip_runtime.h>

#define NB 62
#define NC 5
#define KTOP 49

typedef unsigned short ushort_t;
typedef unsigned int uint_t;

__device__ __forceinline__ float sigmf(float x) {
    return 1.0f / (1.0f + __expf(-x));
}

__device__ __forceinline__ ushort_t f2b(float f) {   // f32 -> bf16 (RNE)
    union { float f; uint_t u; } cv; cv.f = f;
    uint_t r = (cv.u + 0x7fffu + ((cv.u >> 16) & 1u)) >> 16;
    return (ushort_t)r;
}
__device__ __forceinline__ float b2f(ushort_t h) {   // bf16 -> f32 (exact)
    union { uint_t u; float f; } cv; cv.u = ((uint_t)h) << 16;
    return cv.f;
}
__device__ __forceinline__ float blo(uint_t w) {
    union { uint_t u; float f; } cv; cv.u = w << 16; return cv.f;
}
__device__ __forceinline__ float bhi(uint_t w) {
    union { uint_t u; float f; } cv; cv.u = w & 0xffff0000u; return cv.f;
}

__device__ __forceinline__ float tmax62(const float* a) {
    float t0 = a[0], t1 = a[1], t2 = a[2], t3 = a[3];
    #pragma unroll
    for (int m = 4; m < 60; m += 4) {
        t0 = fmaxf(t0, a[m]);     t1 = fmaxf(t1, a[m + 1]);
        t2 = fmaxf(t2, a[m + 2]); t3 = fmaxf(t3, a[m + 3]);
    }
    t0 = fmaxf(t0, a[60]); t1 = fmaxf(t1, a[61]);
    return fmaxf(fmaxf(t0, t1), fmaxf(t2, t3));
}
__device__ __forceinline__ float tsum62(const float* a) {
    float t0 = a[0], t1 = a[1], t2 = a[2], t3 = a[3];
    #pragma unroll
    for (int m = 4; m < 60; m += 4) {
        t0 += a[m]; t1 += a[m + 1]; t2 += a[m + 2]; t3 += a[m + 3];
    }
    t0 += a[60]; t1 += a[61];
    return (t0 + t1) + (t2 + t3);
}

// Repack FC weights into d_ws: fc1w[64][930] -> bf16 [117][64][8] (zero-pad to 936),
// fc2w[64][64] -> f32 [16][64][4].
__global__ void repack_kernel(const float* __restrict__ fc1w,
                              const float* __restrict__ fc2w,
                              ushort_t* __restrict__ w1o,
                              float* __restrict__ w2o) {
    const int i = blockIdx.x * 256 + threadIdx.x;
    if (i < 117 * 64 * 8) {
        const int j = i & 7, o = (i >> 3) & 63, i8 = i >> 9;
        const int src = i8 * 8 + j;
        const float v = (src < 930) ? fc1w[o * 930 + src] : 0.0f;
        w1o[i] = f2b(v);
    } else if (i < 117 * 64 * 8 + 16 * 64 * 4) {
        const int i2 = i - 117 * 64 * 8;
        const int j = i2 & 3, o = (i2 >> 2) & 63, k4 = i2 >> 8;
        w2o[i2] = fc2w[o * 64 + k4 * 4 + j];
    }
}

// One DGCN layer. L==0: input = global x[b] (re-read phase-locally, never live
// across the sort); output -> s_x1. L==1: input = s_x1; output -> f2out regs.
template <int L>
__device__ __forceinline__ void dgcn_layer(
    const int tid, const float* __restrict__ xin_g,
    const float* __restrict__ conv_w, const float* __restrict__ conv_b,
    const float* __restrict__ memp,
    const float* __restrict__ gfc_w, const float* __restrict__ gfc_b,
    const float* __restrict__ gcn_w, const float* __restrict__ gcn_b,
    float (*__restrict__ s_xc4)[4], float (*__restrict__ s_me4)[4],
    float (*__restrict__ s_t45)[2], ushort_t* __restrict__ s_adjh,
    float (*__restrict__ s_x1)[NC], float* __restrict__ f2out)
{
    const float scale = 0.44721359549995793f; // 1/sqrt(5)

    // stage mem: columns 0..3 -> s_me4, column 4 -> s_t45[.][1]
    for (int i = tid; i < NC * NB; i += 64) {
        const int c = i / NB, m = i - c * NB;
        if (c < 4) s_me4[m][c] = memp[i];
        else       s_t45[m][1] = memp[i];
    }

    float cw[25], cbv[5];
    #pragma unroll
    for (int i = 0; i < 25; ++i) cw[i] = conv_w[i];
    #pragma unroll
    for (int i = 0; i < 5; ++i)  cbv[i] = conv_b[i];
    const float w0 = gfc_w[0], w1 = gfc_w[1], b0 = gfc_b[0];

    // ---- conv1x1 on own node (input regs die before the sort) ----
    float xo0 = 0, xo1 = 0, xo2 = 0, xo3 = 0, xo4 = 0;
    if (tid < NB) {
        float xn[5];
        #pragma unroll
        for (int c = 0; c < 5; ++c)
            xn[c] = (L == 0) ? xin_g[c * NB + tid] : s_x1[tid][c];
        xo0 = cbv[0]; xo1 = cbv[1]; xo2 = cbv[2]; xo3 = cbv[3]; xo4 = cbv[4];
        #pragma unroll
        for (int c = 0; c < 5; ++c) {
            xo0 = fmaf(cw[c],      xn[c], xo0);
            xo1 = fmaf(cw[5 + c],  xn[c], xo1);
            xo2 = fmaf(cw[10 + c], xn[c], xo2);
            xo3 = fmaf(cw[15 + c], xn[c], xo3);
            xo4 = fmaf(cw[20 + c], xn[c], xo4);
        }
        s_xc4[tid][0] = xo0; s_xc4[tid][1] = xo1;
        s_xc4[tid][2] = xo2; s_xc4[tid][3] = xo3;
        s_t45[tid][0] = xo4;
    }
    __syncthreads();

    // ---- row phase: thread n owns row n (peak live = r1+r2 ~126, as round 4) ----
    if (tid < NB) {
        float r1[NB];
        float r2[64];
        #pragma unroll
        for (int m = 0; m < NB; ++m) {
            const float4 xc03 = *(const float4*)&s_xc4[m][0];
            const float4 me03 = *(const float4*)&s_me4[m][0];
            const float2 t45  = *(const float2*)&s_t45[m][0];
            float s1 = xo0 * me03.x + xo1 * me03.y + xo2 * me03.z + xo3 * me03.w + xo4 * t45.y;
            float s2 = xo0 * xc03.x + xo1 * xc03.y + xo2 * xc03.z + xo3 * xc03.w + xo4 * t45.x;
            r1[m] = fmaxf(s1 * scale, 0.0f);
            r2[m] = fmaxf(s2 * scale, 0.0f);
        }
        const float mx1 = tmax62(r1);
        #pragma unroll
        for (int m = 0; m < NB; ++m) r1[m] = __expf(r1[m] - mx1);
        const float inv1 = 1.0f / tsum62(r1);
        const float mx2 = tmax62(r2);
        #pragma unroll
        for (int m = 0; m < NB; ++m) r2[m] = __expf(r2[m] - mx2);
        const float inv2 = 1.0f / tsum62(r2);
        #pragma unroll
        for (int m = 0; m < NB; ++m)
            r1[m] = b0 + (r1[m] * inv1) * w0 + (r2[m] * inv2) * w1;
        const float mxa = tmax62(r1);
        #pragma unroll
        for (int m = 0; m < NB; ++m) r1[m] = __expf(r1[m] - mxa);
        const float inva = 1.0f / tsum62(r1);
        #pragma unroll
        for (int m = 0; m < NB; ++m) r1[m] *= inva;

        // ---- 49th-largest via value-only bitonic sort of a copy ----
        #pragma unroll
        for (int m = 0; m < NB; ++m) r2[m] = r1[m];
        r2[62] = INFINITY; r2[63] = INFINITY;
        #pragma unroll
        for (int k = 2; k <= 64; k <<= 1) {
            #pragma unroll
            for (int j = k >> 1; j > 0; j >>= 1) {
                #pragma unroll
                for (int i = 0; i < 64; ++i) {
                    const int p = i ^ j;
                    if (p > i) {
                        const bool up = ((i & k) == 0);
                        const float a = r2[i], c = r2[p];
                        r2[i] = up ? fminf(a, c) : fmaxf(a, c);
                        r2[p] = up ? fmaxf(a, c) : fminf(a, c);
                    }
                }
            }
        }
        const float vth = r2[13]; // 14th smallest == 49th largest

        // ---- tie-aware selection == jax.lax.top_k (lower index first) ----
        int gc0 = 0, gc1 = 0, gc2 = 0, gc3 = 0;
        #pragma unroll
        for (int m = 0; m < 60; m += 4) {
            gc0 += (r1[m] > vth);     gc1 += (r1[m + 1] > vth);
            gc2 += (r1[m + 2] > vth); gc3 += (r1[m + 3] > vth);
        }
        gc0 += (r1[60] > vth); gc1 += (r1[61] > vth);
        const int G = (gc0 + gc1) + (gc2 + gc3);
        int eq = 0;
        #pragma unroll
        for (int m = 0; m < NB; ++m) {
            const bool e  = (r1[m] == vth);
            const bool ss = (r1[m] > vth) || (e && (G + eq) < KTOP);
            // stride 62 bf16 = 124 B = 31 dwords (odd): conflict-free rows AND cols
            s_adjh[tid * NB + m] = f2b(ss ? r1[m] : 0.0f);
            eq += e ? 1 : 0;
        }
    }
    __syncthreads();

    // ---- diffusion + gcn mix + skip: thread m computes output column m ----
    if (tid < NB) {
        const int m = tid;
        float y0 = 0, y1 = 0, y2 = 0, y3 = 0, y4 = 0;
        for (int n = 0; n < NB; ++n) {
            const float a = b2f(s_adjh[n * NB + m]);
            const float4 xv = *(const float4*)&s_xc4[n][0];
            const float  xv4 = s_t45[n][0];
            y0 = fmaf(xv.x, a, y0); y1 = fmaf(xv.y, a, y1); y2 = fmaf(xv.z, a, y2);
            y3 = fmaf(xv.w, a, y3); y4 = fmaf(xv4, a, y4);
        }
        float gwv[25], gbv[5];
        #pragma unroll
        for (int i = 0; i < 25; ++i) gwv[i] = gcn_w[i];
        #pragma unroll
        for (int i = 0; i < 5; ++i)  gbv[i] = gcn_b[i];
        #pragma unroll
        for (int o = 0; o < 5; ++o) {
            const float z = gbv[o] + gwv[o * 5 + 0] * y0 + gwv[o * 5 + 1] * y1 +
                            gwv[o * 5 + 2] * y2 + gwv[o * 5 + 3] * y3 + gwv[o * 5 + 4] * y4;
            const float fi = (L == 0) ? xin_g[o * NB + m] : s_x1[m][o];
            const float zz = z + fi;
            if (L == 0) s_x1[m][o] = zz;
            else        f2out[o]   = zz;
        }
    }
    __syncthreads();
}

// waves_per_eu(2,3): proven round-4 codegen anchor (128 VGPRs, zero scratch).
// LDS ~11.4 KB -> 14 blocks/CU (round 4: 15.9 KB -> 10).
__global__ void __launch_bounds__(64) __attribute__((amdgpu_waves_per_eu(2, 3)))
encoder_kernel(
    const float* __restrict__ g_x,
    const float* __restrict__ c0w, const float* __restrict__ c0b,
    const float* __restrict__ m0,  const float* __restrict__ f0w,
    const float* __restrict__ f0b, const float* __restrict__ g0w,
    const float* __restrict__ g0b,
    const float* __restrict__ c1w, const float* __restrict__ c1b,
    const float* __restrict__ m1,  const float* __restrict__ f1w,
    const float* __restrict__ f1b, const float* __restrict__ g1w,
    const float* __restrict__ g1b,
    const float* __restrict__ caw1, const float* __restrict__ caw2,
    const float* __restrict__ saw,  const float* __restrict__ sab,
    const float* __restrict__ fc1w, const float* __restrict__ fc1b,
    const float* __restrict__ fc2w, const float* __restrict__ fc2b,
    const ushort_t* __restrict__ w1b, const float* __restrict__ w2p,
    const int use_ws,
    float* __restrict__ g_out)
{
    const int b   = blockIdx.x;
    const int tid = threadIdx.x;

    // LDS budget: 992 + 992 + 496 + 7688 + 1240 = 11408 B -> 14 blocks/CU
    __shared__ __align__(16) float s_xc4[NB][4];
    __shared__ __align__(16) float s_me4[NB][4];
    __shared__ __align__(16) float s_t45[NB][2];   // [0]=xc[4], [1]=mem[4]
    __shared__ __align__(16) ushort_t s_adjh[NB * NB];
    __shared__ __align__(16) float s_x1[NB][NC];

    float* const s_g  = (float*)s_adjh;        // 936 f32, alias (adjacency dead)
    float* const s_h1 = ((float*)s_adjh) + 936;

    const float* xin = g_x + (size_t)b * (NC * NB);

    float f2[5] = {0, 0, 0, 0, 0};
    dgcn_layer<0>(tid, xin, c0w, c0b, m0, f0w, f0b, g0w, g0b,
                  s_xc4, s_me4, s_t45, s_adjh, s_x1, nullptr);
    dgcn_layer<1>(tid, xin, c1w, c1b, m1, f1w, f1b, g1w, g1b,
                  s_xc4, s_me4, s_t45, s_adjh, s_x1, f2);

    // ================= CBAM (shuffle-based, all post-sort) =================
    // features: f0 re-read from global (L2-hot), f1 from LDS, f2 in regs
    float f0[5], f1v[5];
    #pragma unroll
    for (int c = 0; c < 5; ++c) {
        f0[c]  = (tid < NB) ? xin[c * NB + tid] : 0.0f;
        f1v[c] = (tid < NB) ? s_x1[tid][c] : 0.0f;
    }

    float mxp[15], avp[15];
    #pragma unroll
    for (int c = 0; c < 15; ++c) {
        const float v = (c < 5) ? f0[c] : (c < 10) ? f1v[c - 5] : f2[c - 10];
        float vm = (tid < NB) ? v : -INFINITY;
        float vs = (tid < NB) ? v : 0.0f;
        #pragma unroll
        for (int off = 32; off > 0; off >>= 1) {
            vm = fmaxf(vm, __shfl_xor(vm, off, 64));
            vs += __shfl_xor(vs, off, 64);
        }
        mxp[c] = vm;
        avp[c] = vs * (1.0f / 62.0f);
    }
    // SE MLP, redundantly on all lanes (uniform weights -> scalar loads)
    float ca[15];
    {
        float hm[3], ha[3];
        #pragma unroll
        for (int o = 0; o < 3; ++o) {
            float am = 0.0f, aa = 0.0f;
            #pragma unroll
            for (int c = 0; c < 15; ++c) {
                const float w = caw1[o * 15 + c];
                am = fmaf(mxp[c], w, am);
                aa = fmaf(avp[c], w, aa);
            }
            hm[o] = fmaxf(am, 0.0f);
            ha[o] = fmaxf(aa, 0.0f);
        }
        #pragma unroll
        for (int c = 0; c < 15; ++c) {
            float t = 0.0f;
            #pragma unroll
            for (int o = 0; o < 3; ++o) t = fmaf(hm[o] + ha[o], caw2[c * 3 + o], t);
            ca[c] = sigmf(t);
        }
    }
    // spatial descriptors; neighbors via lane shuffles
    float og[15];
    float smx = -INFINITY, ssum = 0.0f;
    #pragma unroll
    for (int c = 0; c < 15; ++c) {
        const float fv = (c < 5) ? f0[c] : (c < 10) ? f1v[c - 5] : f2[c - 10];
        const float v = fv * ca[c];
        og[c] = v;
        smx = fmaxf(smx, v);
        ssum += v;
    }
    const float smean = ssum * (1.0f / 15.0f);
    const float sxl = __shfl_up(smx, 1, 64),   sml = __shfl_up(smean, 1, 64);
    const float sxr = __shfl_down(smx, 1, 64), smr = __shfl_down(smean, 1, 64);
    const float mskL = (tid > 0) ? 1.0f : 0.0f;
    const float mskR = (tid < NB - 1) ? 1.0f : 0.0f;
    // 3x1 spatial conv (only kw=1 column of the 3x3 survives W=1 padding)
    float t = sab[0];
    t += mskL * (sxl * saw[1] + sml * saw[10]);
    t += smx * saw[4] + smean * saw[13];
    t += mskR * (sxr * saw[7] + smr * saw[16]);
    const float sa = sigmf(t);

    __syncthreads();  // adjacency dead; region becomes s_g/s_h1
    if (tid < NB) {
        #pragma unroll
        for (int c = 0; c < 15; ++c) {
            const float fv = (c < 5) ? f0[c] : (c < 10) ? f1v[c - 5] : f2[c - 10];
            s_g[c * NB + tid] = og[c] * sa + fv;
        }
    }
    if (tid < 6) s_g[930 + tid] = 0.0f;   // zero pad to 936
    __syncthreads();

    // ================= FC head =================
    if (use_ws) {
        float acc = fc1b[tid];
        const uint4* w1v = (const uint4*)w1b;
        #pragma unroll 4
        for (int i8 = 0; i8 < 117; ++i8) {
            const uint4 wv = w1v[i8 * 64 + tid];
            const float4 ga  = *(const float4*)&s_g[i8 * 8];
            const float4 gb2 = *(const float4*)&s_g[i8 * 8 + 4];
            acc = fmaf(blo(wv.x), ga.x,  acc);
            acc = fmaf(bhi(wv.x), ga.y,  acc);
            acc = fmaf(blo(wv.y), ga.z,  acc);
            acc = fmaf(bhi(wv.y), ga.w,  acc);
            acc = fmaf(blo(wv.z), gb2.x, acc);
            acc = fmaf(bhi(wv.z), gb2.y, acc);
            acc = fmaf(blo(wv.w), gb2.z, acc);
            acc = fmaf(bhi(wv.w), gb2.w, acc);
        }
        s_h1[tid] = fmaxf(acc, 0.0f);
        __syncthreads();
        float acc2 = fc2b[tid];
        #pragma unroll
        for (int k4 = 0; k4 < 16; ++k4) {
            const float4 wv = *(const float4*)(w2p + k4 * 256 + tid * 4);
            const float4 hv = *(const float4*)&s_h1[k4 * 4];
            acc2 = fmaf(wv.x, hv.x, acc2);
            acc2 = fmaf(wv.y, hv.y, acc2);
            acc2 = fmaf(wv.z, hv.z, acc2);
            acc2 = fmaf(wv.w, hv.w, acc2);
        }
        g_out[(size_t)b * 64 + tid] = fmaxf(acc2, 0.0f);
    } else {
        float acc = fc1b[tid];
        const float* wr = fc1w + (size_t)tid * 930;
        #pragma unroll 4
        for (int i = 0; i < 928; i += 2) {
            const float2 wv = *(const float2*)(wr + i);
            const float2 gv = *(const float2*)(&s_g[i]);
            acc = fmaf(wv.x, gv.x, fmaf(wv.y, gv.y, acc));
        }
        acc += wr[928] * s_g[928] + wr[929] * s_g[929];
        s_h1[tid] = fmaxf(acc, 0.0f);
        __syncthreads();
        float acc2 = fc2b[tid];
        const float* wr2 = fc2w + tid * 64;
        #pragma unroll
        for (int k = 0; k < 64; k += 4) {
            const float4 wv = *(const float4*)(wr2 + k);
            acc2 = fmaf(wv.x, s_h1[k], acc2);
            acc2 = fmaf(wv.y, s_h1[k + 1], acc2);
            acc2 = fmaf(wv.z, s_h1[k + 2], acc2);
            acc2 = fmaf(wv.w, s_h1[k + 3], acc2);
        }
        g_out[(size_t)b * 64 + tid] = fmaxf(acc2, 0.0f);
    }
}

extern "C" void kernel_launch(void* const* d_in, const int* in_sizes, int n_in,
                              void* d_out, int out_size, void* d_ws, size_t ws_size,
                              hipStream_t stream) {
    const float* X    = (const float*)d_in[0];
    const float* C0W  = (const float*)d_in[1];
    const float* C0B  = (const float*)d_in[2];
    const float* M0   = (const float*)d_in[3];
    const float* F0W  = (const float*)d_in[4];
    const float* F0B  = (const float*)d_in[5];
    const float* G0W  = (const float*)d_in[6];
    const float* G0B  = (const float*)d_in[7];
    const float* C1W  = (const float*)d_in[8];
    const float* C1B  = (const float*)d_in[9];
    const float* M1   = (const float*)d_in[10];
    const float* F1W  = (const float*)d_in[11];
    const float* F1B  = (const float*)d_in[12];
    const float* G1W  = (const float*)d_in[13];
    const float* G1B  = (const float*)d_in[14];
    const float* CAW1 = (const float*)d_in[15];
    const float* CAW2 = (const float*)d_in[16];
    const float* SAW  = (const float*)d_in[17];
    const float* SAB  = (const float*)d_in[18];
    const float* FC1W = (const float*)d_in[19];
    const float* FC1B = (const float*)d_in[20];
    const float* FC2W = (const float*)d_in[21];
    const float* FC2B = (const float*)d_in[22];

    const int B = in_sizes[0] / (NC * NB);

    const size_t W1_BYTES = 117 * 64 * 8 * sizeof(ushort_t); // 119808
    const size_t W2_BYTES = 16 * 64 * 4 * sizeof(float);     // 16384
    const int use_ws = (ws_size >= W1_BYTES + W2_BYTES) ? 1 : 0;
    ushort_t* w1b = (ushort_t*)d_ws;
    float*    w2p = (float*)((char*)d_ws + W1_BYTES);

    if (use_ws) {
        repack_kernel<<<250, 256, 0, stream>>>(FC1W, FC2W, w1b, w2p);
    }

    encoder_kernel<<<B, 64, 0, stream>>>(
        X, C0W, C0B, M0, F0W, F0B, G0W, G0B,
        C1W, C1B, M1, F1W, F1B, G1W, G1B,
        CAW1, CAW2, SAW, SAB, FC1W, FC1B, FC2W, FC2B,
        w1b, w2p, use_ws,
        (float*)d_out);
}